// Round 8
// baseline (1310.071 us; speedup 1.0000x reference)
//
#include <hip/hip_runtime.h>
#include <math.h>

typedef __attribute__((ext_vector_type(8))) short short8v;
typedef __attribute__((ext_vector_type(4))) float float4v;

static __device__ __forceinline__ unsigned short f2bf(float f) {
  union { float f; unsigned int u; } v; v.f = f;
  unsigned int r = v.u + 0x7fffu + ((v.u >> 16) & 1u);
  return (unsigned short)(r >> 16);
}
static __device__ __forceinline__ void wave_fence() {
  asm volatile("s_waitcnt lgkmcnt(0)" ::: "memory");
  __builtin_amdgcn_sched_barrier(0);
}

// ---------------- K1: KNN via bitonic selection ----------------
// rec row layout (88 floats): [0..2]=sx,sy,sz [3]=0, then per k: [4+4k..] = {dis,rx,ry,rz}
__global__ __launch_bounds__(512) void k_knn(const float* __restrict__ x,
                                             float* __restrict__ rec,
                                             int*   __restrict__ idxArr,
                                             float* __restrict__ mmPart) {
  __shared__ float px[2048], py[2048], pz[2048];
  __shared__ unsigned long long listK[8][64];
  __shared__ float wmn[8], wmx[8];

  const int b = blockIdx.y;
  const int t = threadIdx.x;
  const float* xb = x + (size_t)b * 3 * 2048;
  for (int i = t; i < 2048; i += 512) {
    px[i] = xb[i];
    py[i] = xb[2048 + i];
    pz[i] = xb[4096 + i];
  }
  __syncthreads();

  const int w = t >> 6, lane = t & 63;
  const int n = blockIdx.x * 8 + w;
  const float sx = px[n], sy = py[n], sz = pz[n];

  float lmin = 1e30f;
  for (int j = lane; j < 2048; j += 64) {
    float dx = px[j] - sx, dy = py[j] - sy, dz = pz[j] - sz;
    float d = fmaf(dx, dx, fmaf(dy, dy, dz * dz));
    lmin = fminf(lmin, d);
  }
  unsigned k32 = __float_as_uint(lmin);
  #pragma unroll
  for (int kk = 2; kk <= 64; kk <<= 1) {
    #pragma unroll
    for (int jj = kk >> 1; jj > 0; jj >>= 1) {
      unsigned o = __shfl_xor(k32, jj);
      bool keepMin = (((lane & jj) == 0) == ((lane & kk) == 0));
      unsigned mn = k32 < o ? k32 : o;
      unsigned mx = k32 < o ? o : k32;
      k32 = keepMin ? mn : mx;
    }
  }
  const float T = __uint_as_float(__shfl(k32, 19));

  int base = 0;
  for (int j = lane; j < 2048; j += 64) {
    float dx = px[j] - sx, dy = py[j] - sy, dz = pz[j] - sz;
    float d = fmaf(dx, dx, fmaf(dy, dy, dz * dz));
    bool hit = (d <= T);
    unsigned long long mask = __ballot(hit);
    if (hit) {
      int slot = base + __popcll(mask & ((1ull << lane) - 1ull));
      if (slot < 64)
        listK[w][slot] = (((unsigned long long)__float_as_uint(d)) << 32) | (unsigned)j;
    }
    base += __popcll(mask);
  }
  const int M = base;

  float myD = 0.f; int myJ = 0;
  if (M > 64) {
    float lastD = -1.f; int lastJ = -1;
    for (int r = 0; r < 20; ++r) {
      float bd = 1e30f; int bj = 0x7fffffff;
      for (int j = lane; j < 2048; j += 64) {
        float dx = px[j] - sx, dy = py[j] - sy, dz = pz[j] - sz;
        float d = fmaf(dx, dx, fmaf(dy, dy, dz * dz));
        bool valid = (d > lastD) || (d == lastD && j > lastJ);
        if (valid && (d < bd || (d == bd && j < bj))) { bd = d; bj = j; }
      }
      for (int s = 1; s < 64; s <<= 1) {
        float od = __shfl_xor(bd, s); int oj = __shfl_xor(bj, s);
        if (od < bd || (od == bd && oj < bj)) { bd = od; bj = oj; }
      }
      if (lane == r) { myD = bd; myJ = bj; }
      lastD = bd; lastJ = bj;
    }
  } else {
    asm volatile("s_waitcnt lgkmcnt(0)" ::: "memory");
    unsigned long long key = (lane < M) ? listK[w][lane] : 0xFFFFFFFFFFFFFFFFull;
    #pragma unroll
    for (int kk = 2; kk <= 64; kk <<= 1) {
      #pragma unroll
      for (int jj = kk >> 1; jj > 0; jj >>= 1) {
        unsigned long long o = __shfl_xor(key, jj);
        bool keepMin = (((lane & jj) == 0) == ((lane & kk) == 0));
        unsigned long long mn = key < o ? key : o;
        unsigned long long mx = key < o ? o : key;
        key = keepMin ? mn : mx;
      }
    }
    myD = __uint_as_float((unsigned)(key >> 32));
    myJ = (int)(unsigned)(key & 0xFFFFFFFFu);
  }

  float row_mn = 1e30f, row_mx = -1e30f;
  const size_t row = (size_t)b * 2048 + n;
  if (lane < 20) {
    int j = myJ;
    idxArr[row * 20 + lane] = j;
    float rx = px[j] - sx, ry = py[j] - sy, rz = pz[j] - sz;
    float dis = sqrtf(myD);
    float* rp = rec + row * 88;
    float4 r4; r4.x = dis; r4.y = rx; r4.z = ry; r4.w = rz;
    *(float4*)(rp + 4 + 4 * lane) = r4;
    row_mn = fminf(fminf(rx, ry), fminf(rz, dis));
    row_mx = fmaxf(fmaxf(rx, ry), fmaxf(rz, dis));
    if (lane == 0) {
      rp[0] = sx; rp[1] = sy; rp[2] = sz; rp[3] = 0.f;
      row_mn = fminf(row_mn, fminf(fminf(sx, sy), sz));
      row_mx = fmaxf(row_mx, fmaxf(fmaxf(sx, sy), sz));
    }
  }
  for (int s = 1; s < 64; s <<= 1) {
    row_mn = fminf(row_mn, __shfl_xor(row_mn, s));
    row_mx = fmaxf(row_mx, __shfl_xor(row_mx, s));
  }
  if (lane == 0) { wmn[w] = row_mn; wmx[w] = row_mx; }
  __syncthreads();
  if (t == 0) {
    float mn = wmn[0], mx = wmx[0];
    #pragma unroll
    for (int i = 1; i < 8; ++i) { mn = fminf(mn, wmn[i]); mx = fmaxf(mx, wmx[i]); }
    int bid = blockIdx.y * 256 + blockIdx.x;
    mmPart[bid * 2]     = mn;
    mmPart[bid * 2 + 1] = mx;
  }
}

// ---------------- K1b: minmax reduce, M matrix, extended W1E weights ----------------
// W1E[o][u] (K=288): u<64: f_rep W1 cols; 64..127: f_diff; 128..191: E_d=Wxd@Wm;
// 192..255: E_r=Wxr@Wm; 256: w1b=Wxr@bmlp; 257..287: 0.   cp(c)=(c%48)*4+c/48.
__global__ __launch_bounds__(256) void k_prep(const float* __restrict__ A,
                                              const float* __restrict__ kern,
                                              const float* __restrict__ W1,
                                              const float* __restrict__ Wmlp,
                                              const float* __restrict__ bmlp,
                                              const float* __restrict__ mmPart,
                                              float* __restrict__ scal,
                                              unsigned short* __restrict__ W1E) {
  __shared__ float smn[256], smx[256];
  const int t = threadIdx.x;
  float mn = 1e30f, mx = -1e30f;
  for (int i = t; i < 4096; i += 256) {
    mn = fminf(mn, mmPart[i * 2]);
    mx = fmaxf(mx, mmPart[i * 2 + 1]);
  }
  smn[t] = mn; smx[t] = mx;
  __syncthreads();
  for (int s = 128; s > 0; s >>= 1) {
    if (t < s) { smn[t] = fminf(smn[t], smn[t + s]); smx[t] = fmaxf(smx[t], smx[t + s]); }
    __syncthreads();
  }
  if (t == 0) scal[0] = smn[0] / (smx[0] - smn[0]);   // c  (ref precedence: x - mn/(mx-mn))
  if (t < 24) {
    int d = t >> 3, e = t & 7;
    float s = 0.f;
    for (int d2 = 0; d2 < 3; ++d2)
      s += 0.5f * (A[d * 3 + d2] + A[d2 * 3 + d]) * kern[d2 * 8 + e];
    scal[1 + t] = s;
  }
  for (int i = t; i < 18432; i += 256) {
    int o = i / 288, u = i % 288;
    float v;
    if (u < 64) {
      int c = u;
      v = W1[o * 192 + (c % 48) * 4 + c / 48];
    } else if (u < 128) {
      int c = 96 + (u - 64);
      v = W1[o * 192 + (c % 48) * 4 + c / 48];
    } else if (u < 192) {
      int m = u - 128; float s = 0.f;
      for (int j = 0; j < 32; ++j) {
        int c = 160 + j;
        s += W1[o * 192 + (c % 48) * 4 + c / 48] * Wmlp[j * 64 + m];
      }
      v = s;
    } else if (u < 256) {
      int m = u - 192; float s = 0.f;
      for (int j = 0; j < 32; ++j) {
        int c = 64 + j;
        s += W1[o * 192 + (c % 48) * 4 + c / 48] * Wmlp[j * 64 + m];
      }
      v = s;
    } else if (u == 256) {
      float s = 0.f;
      for (int j = 0; j < 32; ++j) {
        int c = 64 + j;
        s += W1[o * 192 + (c % 48) * 4 + c / 48] * bmlp[j];
      }
      v = s;
    } else {
      v = 0.f;
    }
    W1E[o * 288 + u] = f2bf(v);
  }
}

// ---------------- K2: transpose feature (B,64,N) -> featN (B,N,64) ----------------
__global__ __launch_bounds__(256) void k_transpose(const float* __restrict__ f,
                                                   float* __restrict__ fN) {
  __shared__ float tile[64][65];
  const int b = blockIdx.y, n0 = blockIdx.x * 64, t = threadIdx.x;
  const float* fb = f + (size_t)b * 64 * 2048;
  for (int i = t; i < 4096; i += 256) {
    int c = i >> 6, nl = i & 63;
    tile[c][nl] = fb[c * 2048 + n0 + nl];
  }
  __syncthreads();
  float* out = fN + ((size_t)b * 2048 + n0) * 64;
  for (int i = t; i < 4096; i += 256) {
    int nl = i >> 6, c = i & 63;
    out[nl * 64 + c] = tile[c][nl];
  }
}

// ---------------- K3: main — ff in regs, 64-lane softmax, x-path folded into h-GEMM ----------------
// LDS: aggB 32*296*2=18944 + recL 1408 + permL 2560 + selfFL 1024 + colsumL 128 = 24064 B
// -> 6 blocks/CU (24 waves). 2 wave_fences + 1 __syncthreads per wave.
__global__ __launch_bounds__(256, 6) void k_main(const float* __restrict__ rec,
    const int* __restrict__ idxArr, const float* __restrict__ featN,
    const float* __restrict__ scal, const unsigned short* __restrict__ W1E,
    const float* __restrict__ Bf, const float* __restrict__ onePad,
    const float* __restrict__ b1, const float* __restrict__ Wout,
    float* __restrict__ hT) {
  __shared__ __align__(16) unsigned short aggB[32 * 296];
  __shared__ __align__(16) float recL[4][88];
  __shared__ float permL[4][160];
  __shared__ float selfFL[4][64];
  __shared__ float colsumL[4][8];

  const int t = threadIdx.x;
  const int pt = t >> 6, lane = t & 63;
  const int row = blockIdx.x * 4 + pt;
  const int b = row >> 11;
  const int fr = lane & 15, fg = lane >> 4;
  const int m31 = lane & 31, e7 = lane & 7, k4 = lane >> 3;

  // ---- phase A: all global constants -> regs ----
  float bf_[7];
  #pragma unroll
  for (int d = 0; d < 7; ++d) bf_[d] = Bf[d * 32 + m31];
  const float c0 = scal[0];
  const float M0 = scal[1 + e7], M1 = scal[9 + e7], M2 = scal[17 + e7];
  const float op0v = onePad[lane];
  const float op1v = onePad[64 + lane];
  const float op2v = (lane < 32) ? onePad[128 + lane] : 0.f;
  const int ntb = (pt >> 1) * 2;
  const int col = (ntb + (fg & 1)) * 16 + fr;
  const float b1v = b1[col];

  // ---- phase B: per-row loads ----
  if (lane < 22)
    *(float4v*)&recL[pt][4 * lane] = *(const float4v*)(rec + (size_t)row * 88 + 4 * lane);
  selfFL[pt][lane] = featN[(size_t)row * 64 + lane];
  int myidx = (lane < 20) ? idxArr[(size_t)row * 20 + lane] : 0;

  // ---- phase C: issue all 20 gathers (consumed in agg, much later) ----
  float gv[20];
  {
    const float* fNb = featN + (((size_t)b << 11) * 64);
    #pragma unroll
    for (int k = 0; k < 20; ++k) {
      int j = __shfl(myidx, k);
      gv[k] = fNb[(size_t)j * 64 + lane];
    }
  }

  // zero aggB pad cols 257..287 of this wave's 8 rows (weights there are 0, but
  // keep A finite: uninitialized LDS could hold NaN; NaN*0 = NaN)
  if (lane >= 32 && lane < 63) {
    #pragma unroll
    for (int e = 0; e < 8; ++e)
      aggB[(pt * 8 + e) * 296 + 225 + lane] = 0;
  }
  wave_fence();   // recL visible (same wave)

  // ---- perm + topkmax softmax, 64-lane: lane = (k4 = lane>>3, e = lane&7) ----
  {
    float4v r0 = *(const float4v*)&recL[pt][4 + 4 * k4];
    float4v r1 = *(const float4v*)&recL[pt][4 + 4 * (k4 + 8)];
    float lg0 = fmaf(r0[1], M0, fmaf(r0[2], M1, fmaf(r0[3], M2, op0v)));
    float lg1 = fmaf(r1[1], M0, fmaf(r1[2], M1, fmaf(r1[3], M2, op1v)));
    float lg2 = -1e30f;
    if (lane < 32) {
      float4v r2 = *(const float4v*)&recL[pt][4 + 4 * (k4 + 16)];
      lg2 = fmaf(r2[1], M0, fmaf(r2[2], M1, fmaf(r2[3], M2, op2v)));
    }
    float mx = fmaxf(fmaxf(lg0, lg1), lg2);
    mx = fmaxf(mx, __shfl_xor(mx, 8));
    mx = fmaxf(mx, __shfl_xor(mx, 16));
    mx = fmaxf(mx, __shfl_xor(mx, 32));
    float e0 = __expf(lg0 - mx), e1 = __expf(lg1 - mx);
    float e2 = (lane < 32) ? __expf(lg2 - mx) : 0.f;
    float s1 = e0 + e1 + e2;
    s1 += __shfl_xor(s1, 8); s1 += __shfl_xor(s1, 16); s1 += __shfl_xor(s1, 32);
    float inv = 1.f / s1;
    float q0 = e0 * inv, q1 = e1 * inv, q2 = e2 * inv;
    q0 = (q0 > 0.05f) ? q0 : 0.f;
    q1 = (q1 > 0.05f) ? q1 : 0.f;
    q2 = (q2 > 0.05f) ? q2 : 0.f;
    float s2 = q0 + q1 + q2;
    s2 += __shfl_xor(s2, 8); s2 += __shfl_xor(s2, 16); s2 += __shfl_xor(s2, 32);
    float inv2 = 1.f / (s2 + 1e-6f);
    permL[pt][lane]      = q0 * inv2;
    permL[pt][64 + lane] = q1 * inv2;
    if (lane < 32) permL[pt][128 + lane] = q2 * inv2;
    if (k4 == 0) colsumL[pt][e7] = s2 * inv2;
  }

  // ---- Fourier features, fully in registers: lane = m (0..31 sin, 32..63 cos) ----
  float ffk[20];
  {
    const float sumB = ((bf_[0] + bf_[1]) + (bf_[2] + bf_[3]))
                     + ((bf_[4] + bf_[5]) + bf_[6]);
    float basev = recL[pt][0] * bf_[0];
    basev = fmaf(recL[pt][1], bf_[1], basev);
    basev = fmaf(recL[pt][2], bf_[2], basev);
    basev = fmaf(-c0, sumB, basev);
    const bool iscos = (lane >= 32);
    #pragma unroll
    for (int k = 0; k < 20; ++k) {
      float4v r4 = *(const float4v*)&recL[pt][4 + 4 * k];
      float s = basev;
      s = fmaf(r4[1], bf_[3], s);
      s = fmaf(r4[2], bf_[4], s);
      s = fmaf(r4[3], bf_[5], s);
      s = fmaf(r4[0], bf_[6], s);
      float fs, sv, cv;
      asm("v_fract_f32 %0, %1" : "=v"(fs) : "v"(s));
      asm("v_sin_f32 %0, %1"   : "=v"(sv) : "v"(fs));
      asm("v_cos_f32 %0, %1"   : "=v"(cv) : "v"(fs));
      ffk[k] = iscos ? cv : sv;
    }
  }
  wave_fence();   // permL / colsumL visible (same wave)

  // ---- agg: accQ (x-path) and accF (f_neigh) in one pass over perm ----
  float cs[8];
  {
    float4v c01 = *(const float4v*)&colsumL[pt][0];
    float4v c23 = *(const float4v*)&colsumL[pt][4];
    cs[0] = c01[0]; cs[1] = c01[1]; cs[2] = c01[2]; cs[3] = c01[3];
    cs[4] = c23[0]; cs[5] = c23[1]; cs[6] = c23[2]; cs[7] = c23[3];
  }
  float accQ[8], accF[8];
  #pragma unroll
  for (int e = 0; e < 8; ++e) { accQ[e] = 0.f; accF[e] = 0.f; }
  #pragma unroll
  for (int k = 0; k < 20; ++k) {
    float4v p0 = *(const float4v*)&permL[pt][k * 8];
    float4v p1 = *(const float4v*)&permL[pt][k * 8 + 4];
    const float fv = ffk[k], gvv = gv[k];
    accQ[0] = fmaf(fv, p0[0], accQ[0]); accQ[1] = fmaf(fv, p0[1], accQ[1]);
    accQ[2] = fmaf(fv, p0[2], accQ[2]); accQ[3] = fmaf(fv, p0[3], accQ[3]);
    accQ[4] = fmaf(fv, p1[0], accQ[4]); accQ[5] = fmaf(fv, p1[1], accQ[5]);
    accQ[6] = fmaf(fv, p1[2], accQ[6]); accQ[7] = fmaf(fv, p1[3], accQ[7]);
    accF[0] = fmaf(gvv, p0[0], accF[0]); accF[1] = fmaf(gvv, p0[1], accF[1]);
    accF[2] = fmaf(gvv, p0[2], accF[2]); accF[3] = fmaf(gvv, p0[3], accF[3]);
    accF[4] = fmaf(gvv, p1[0], accF[4]); accF[5] = fmaf(gvv, p1[1], accF[5]);
    accF[6] = fmaf(gvv, p1[2], accF[6]); accF[7] = fmaf(gvv, p1[3], accF[7]);
  }

  // ---- aggB writes: [f_rep | f_diff | Q-ff0cs | ff0cs | cs | 0pad] ----
  {
    const float f0 = gv[0], x0 = ffk[0];
    #pragma unroll
    for (int e = 0; e < 8; ++e) {
      unsigned short* rb = aggB + (size_t)(pt * 8 + e) * 296;
      const float cse = cs[e];
      const float frep = f0 * cse;
      const float xrep = x0 * cse;
      rb[lane]       = f2bf(frep);
      rb[64 + lane]  = f2bf(accF[e] - frep);
      rb[128 + lane] = f2bf(accQ[e] - xrep);
      rb[192 + lane] = f2bf(xrep);
      if (lane == 0) rb[256] = f2bf(cse);
    }
  }
  __syncthreads();

  // ---- h-stage MFMA: (32 rows x 288) @ W1E^T(288 x 64) ----
  const int mt = pt & 1;
  float4v h0 = float4v{0.f, 0.f, 0.f, 0.f};
  float4v h1 = float4v{0.f, 0.f, 0.f, 0.f};
  {
    const unsigned short* aRow = aggB + (mt * 16 + fr) * 296;
    const unsigned short* w1p0 = W1E + ((ntb * 16 + fr) * 288);
    const unsigned short* w1p1 = W1E + (((ntb + 1) * 16 + fr) * 288);
    #pragma unroll
    for (int ks = 0; ks < 9; ++ks) {
      short8v a   = *(const short8v*)(aRow + ks * 32 + fg * 8);
      short8v b0  = *(const short8v*)(w1p0 + ks * 32 + fg * 8);
      short8v b1f = *(const short8v*)(w1p1 + ks * 32 + fg * 8);
      h0 = __builtin_amdgcn_mfma_f32_16x16x32_bf16(a, b0,  h0, 0, 0, 0);
      h1 = __builtin_amdgcn_mfma_f32_16x16x32_bf16(a, b1f, h1, 0, 0, 0);
    }
  }

  // ---- post: max over e (4 local + shfl16), +b1, gelu, residual, store ----
  {
    float m0 = fmaxf(fmaxf(h0[0], h0[1]), fmaxf(h0[2], h0[3]));
    float m1 = fmaxf(fmaxf(h1[0], h1[1]), fmaxf(h1[2], h1[3]));
    m0 = fmaxf(m0, __shfl_xor(m0, 16));
    m1 = fmaxf(m1, __shfl_xor(m1, 16));
    const int p_loc = 2 * mt + (fg >> 1);
    float hm = ((fg & 1) ? m1 : m0) + b1v;
    float g = 0.5f * hm * (1.f + erff(hm * 0.7071067811865476f));
    float res = 0.f;
    const float* wr = Wout + col * 64;
    #pragma unroll
    for (int c = 0; c < 64; c += 4) {
      float4 wv = *(const float4*)(wr + c);
      res = fmaf(wv.x, selfFL[p_loc][c],     res);
      res = fmaf(wv.y, selfFL[p_loc][c + 1], res);
      res = fmaf(wv.z, selfFL[p_loc][c + 2], res);
      res = fmaf(wv.w, selfFL[p_loc][c + 3], res);
    }
    hT[(size_t)(blockIdx.x * 4 + p_loc) * 64 + col] = g + res;
  }
}

// ---------------- K4: BN statistics (deterministic two-stage) ----------------
__global__ __launch_bounds__(256) void k_bnstat(const float* __restrict__ hT,
                                                float* __restrict__ part) {
  const int bk = blockIdx.x;
  const int t = threadIdx.x;
  const int o = t & 63, rg = t >> 6;
  float s = 0.f, s2 = 0.f;
  for (int r = bk * 512 + rg; r < (bk + 1) * 512; r += 4) {
    float v = hT[(size_t)r * 64 + o];
    s += v;
    s2 = fmaf(v, v, s2);
  }
  __shared__ float ls[256], ls2[256];
  ls[t] = s; ls2[t] = s2;
  __syncthreads();
  if (t < 64) {
    float a  = ls[t] + ls[t + 64] + ls[t + 128] + ls[t + 192];
    float a2 = ls2[t] + ls2[t + 64] + ls2[t + 128] + ls2[t + 192];
    part[(bk * 64 + t) * 2]     = a;
    part[(bk * 64 + t) * 2 + 1] = a2;
  }
}

__global__ void k_bnfinal(const float* __restrict__ part, float* __restrict__ stats) {
  const int t = threadIdx.x;
  if (t < 64) {
    float s = 0.f, s2 = 0.f;
    for (int bk = 0; bk < 64; ++bk) {
      s  += part[(bk * 64 + t) * 2];
      s2 += part[(bk * 64 + t) * 2 + 1];
    }
    float mu  = s * (1.f / 32768.f);
    float var = s2 * (1.f / 32768.f) - mu * mu;
    stats[t * 2]     = mu;
    stats[t * 2 + 1] = 1.f / sqrtf(var + 1e-5f);
  }
}

// ---------------- K5: BN apply + transpose to (B,64,N) ----------------
__global__ __launch_bounds__(256) void k_bnapply(const float* __restrict__ hT,
                                                 const float* __restrict__ stats,
                                                 const float* __restrict__ gamma,
                                                 const float* __restrict__ beta,
                                                 float* __restrict__ out) {
  __shared__ float tile[64][65];
  __shared__ float sMu[64], sRs[64], sGa[64], sBe[64];
  const int t = threadIdx.x;
  const int r0 = blockIdx.x * 64;
  if (t < 64) {
    sMu[t] = stats[t * 2];
    sRs[t] = stats[t * 2 + 1];
    sGa[t] = gamma[t];
    sBe[t] = beta[t];
  }
  __syncthreads();
  for (int i = t; i < 4096; i += 256) {
    int rl = i >> 6, o = i & 63;
    float v = hT[(size_t)(r0 + rl) * 64 + o];
    tile[rl][o] = fmaf((v - sMu[o]) * sRs[o], sGa[o], sBe[o]);
  }
  __syncthreads();
  const int b = r0 >> 11, n0 = r0 & 2047;
  for (int i = t; i < 4096; i += 256) {
    int o = i >> 6, nl = i & 63;
    out[((size_t)b * 64 + o) * 2048 + n0 + nl] = tile[nl][o];
  }
}

// ---------------- launch ----------------
extern "C" void kernel_launch(void* const* d_in, const int* in_sizes, int n_in,
                              void* d_out, int out_size, void* d_ws, size_t ws_size,
                              hipStream_t stream) {
  const float* x       = (const float*)d_in[0];
  const float* feature = (const float*)d_in[1];
  const float* A       = (const float*)d_in[2];
  const float* Bf      = (const float*)d_in[3];
  const float* kern    = (const float*)d_in[4];
  const float* onePad  = (const float*)d_in[5];
  const float* Wmlp    = (const float*)d_in[6];
  const float* bmlp    = (const float*)d_in[7];
  const float* W1      = (const float*)d_in[8];
  const float* b1      = (const float*)d_in[9];
  const float* gamma   = (const float*)d_in[10];
  const float* beta    = (const float*)d_in[11];
  const float* Wout    = (const float*)d_in[12];

  char* ws = (char*)d_ws;
  float* rec           = (float*)(ws);                       // 11,534,336
  int*   idxA          = (int*)  (ws + 11534336);            // -> 14,155,776
  float* featN         = (float*)(ws + 14155776);            // -> 22,544,384
  float* hT            = (float*)(ws + 22544384);            // -> 30,932,992
  unsigned short* W1E  = (unsigned short*)(ws + 30932992);   // 36,864 -> 30,969,856
  float* mmPart        = (float*)(ws + 30969856);            // 32,768 -> 31,002,624
  float* scal          = (float*)(ws + 31002624);            // 256    -> 31,002,880
  float* bnPart        = (float*)(ws + 31002880);            // 32,768 -> 31,035,648
  float* bnStats       = (float*)(ws + 31035648);            // 512    -> 31,036,160

  k_knn<<<dim3(256, 16), 512, 0, stream>>>(x, rec, idxA, mmPart);
  k_prep<<<1, 256, 0, stream>>>(A, kern, W1, Wmlp, bmlp, mmPart, scal, W1E);
  k_transpose<<<dim3(32, 16), 256, 0, stream>>>(feature, featN);
  k_main<<<8192, 256, 0, stream>>>(rec, idxA, featN, scal, W1E,
                                   Bf, onePad, b1, Wout, hT);
  k_bnstat<<<64, 256, 0, stream>>>(hT, bnPart);
  k_bnfinal<<<1, 64, 0, stream>>>(bnPart, bnStats);
  k_bnapply<<<512, 256, 0, stream>>>(hT, bnStats, gamma, beta, (float*)d_out);
}

// Round 9
// 665.325 us; speedup vs baseline: 1.9691x; 1.9691x over previous
//
#include <hip/hip_runtime.h>
#include <math.h>

typedef __attribute__((ext_vector_type(8))) short short8v;
typedef __attribute__((ext_vector_type(4))) float float4v;

static __device__ __forceinline__ unsigned short f2bf(float f) {
  union { float f; unsigned int u; } v; v.f = f;
  unsigned int r = v.u + 0x7fffu + ((v.u >> 16) & 1u);
  return (unsigned short)(r >> 16);
}
static __device__ __forceinline__ void wave_fence() {
  asm volatile("s_waitcnt lgkmcnt(0)" ::: "memory");
  __builtin_amdgcn_sched_barrier(0);
}

// ---------------- K1: KNN via bitonic selection ----------------
// rec row layout (88 floats): [0..2]=sx,sy,sz [3]=0, then per k: [4+4k..] = {dis,rx,ry,rz}
__global__ __launch_bounds__(512) void k_knn(const float* __restrict__ x,
                                             float* __restrict__ rec,
                                             int*   __restrict__ idxArr,
                                             float* __restrict__ mmPart) {
  __shared__ float px[2048], py[2048], pz[2048];
  __shared__ unsigned long long listK[8][64];
  __shared__ float wmn[8], wmx[8];

  const int b = blockIdx.y;
  const int t = threadIdx.x;
  const float* xb = x + (size_t)b * 3 * 2048;
  for (int i = t; i < 2048; i += 512) {
    px[i] = xb[i];
    py[i] = xb[2048 + i];
    pz[i] = xb[4096 + i];
  }
  __syncthreads();

  const int w = t >> 6, lane = t & 63;
  const int n = blockIdx.x * 8 + w;
  const float sx = px[n], sy = py[n], sz = pz[n];

  float lmin = 1e30f;
  for (int j = lane; j < 2048; j += 64) {
    float dx = px[j] - sx, dy = py[j] - sy, dz = pz[j] - sz;
    float d = fmaf(dx, dx, fmaf(dy, dy, dz * dz));
    lmin = fminf(lmin, d);
  }
  unsigned k32 = __float_as_uint(lmin);
  #pragma unroll
  for (int kk = 2; kk <= 64; kk <<= 1) {
    #pragma unroll
    for (int jj = kk >> 1; jj > 0; jj >>= 1) {
      unsigned o = __shfl_xor(k32, jj);
      bool keepMin = (((lane & jj) == 0) == ((lane & kk) == 0));
      unsigned mn = k32 < o ? k32 : o;
      unsigned mx = k32 < o ? o : k32;
      k32 = keepMin ? mn : mx;
    }
  }
  const float T = __uint_as_float(__shfl(k32, 19));

  int base = 0;
  for (int j = lane; j < 2048; j += 64) {
    float dx = px[j] - sx, dy = py[j] - sy, dz = pz[j] - sz;
    float d = fmaf(dx, dx, fmaf(dy, dy, dz * dz));
    bool hit = (d <= T);
    unsigned long long mask = __ballot(hit);
    if (hit) {
      int slot = base + __popcll(mask & ((1ull << lane) - 1ull));
      if (slot < 64)
        listK[w][slot] = (((unsigned long long)__float_as_uint(d)) << 32) | (unsigned)j;
    }
    base += __popcll(mask);
  }
  const int M = base;

  float myD = 0.f; int myJ = 0;
  if (M > 64) {
    float lastD = -1.f; int lastJ = -1;
    for (int r = 0; r < 20; ++r) {
      float bd = 1e30f; int bj = 0x7fffffff;
      for (int j = lane; j < 2048; j += 64) {
        float dx = px[j] - sx, dy = py[j] - sy, dz = pz[j] - sz;
        float d = fmaf(dx, dx, fmaf(dy, dy, dz * dz));
        bool valid = (d > lastD) || (d == lastD && j > lastJ);
        if (valid && (d < bd || (d == bd && j < bj))) { bd = d; bj = j; }
      }
      for (int s = 1; s < 64; s <<= 1) {
        float od = __shfl_xor(bd, s); int oj = __shfl_xor(bj, s);
        if (od < bd || (od == bd && oj < bj)) { bd = od; bj = oj; }
      }
      if (lane == r) { myD = bd; myJ = bj; }
      lastD = bd; lastJ = bj;
    }
  } else {
    asm volatile("s_waitcnt lgkmcnt(0)" ::: "memory");
    unsigned long long key = (lane < M) ? listK[w][lane] : 0xFFFFFFFFFFFFFFFFull;
    #pragma unroll
    for (int kk = 2; kk <= 64; kk <<= 1) {
      #pragma unroll
      for (int jj = kk >> 1; jj > 0; jj >>= 1) {
        unsigned long long o = __shfl_xor(key, jj);
        bool keepMin = (((lane & jj) == 0) == ((lane & kk) == 0));
        unsigned long long mn = key < o ? key : o;
        unsigned long long mx = key < o ? o : key;
        key = keepMin ? mn : mx;
      }
    }
    myD = __uint_as_float((unsigned)(key >> 32));
    myJ = (int)(unsigned)(key & 0xFFFFFFFFu);
  }

  float row_mn = 1e30f, row_mx = -1e30f;
  const size_t row = (size_t)b * 2048 + n;
  if (lane < 20) {
    int j = myJ;
    idxArr[row * 20 + lane] = j;
    float rx = px[j] - sx, ry = py[j] - sy, rz = pz[j] - sz;
    float dis = sqrtf(myD);
    float* rp = rec + row * 88;
    float4 r4; r4.x = dis; r4.y = rx; r4.z = ry; r4.w = rz;
    *(float4*)(rp + 4 + 4 * lane) = r4;
    row_mn = fminf(fminf(rx, ry), fminf(rz, dis));
    row_mx = fmaxf(fmaxf(rx, ry), fmaxf(rz, dis));
    if (lane == 0) {
      rp[0] = sx; rp[1] = sy; rp[2] = sz; rp[3] = 0.f;
      row_mn = fminf(row_mn, fminf(fminf(sx, sy), sz));
      row_mx = fmaxf(row_mx, fmaxf(fmaxf(sx, sy), sz));
    }
  }
  for (int s = 1; s < 64; s <<= 1) {
    row_mn = fminf(row_mn, __shfl_xor(row_mn, s));
    row_mx = fmaxf(row_mx, __shfl_xor(row_mx, s));
  }
  if (lane == 0) { wmn[w] = row_mn; wmx[w] = row_mx; }
  __syncthreads();
  if (t == 0) {
    float mn = wmn[0], mx = wmx[0];
    #pragma unroll
    for (int i = 1; i < 8; ++i) { mn = fminf(mn, wmn[i]); mx = fmaxf(mx, wmx[i]); }
    int bid = blockIdx.y * 256 + blockIdx.x;
    mmPart[bid * 2]     = mn;
    mmPart[bid * 2 + 1] = mx;
  }
}

// ---------------- K1b: minmax reduce, M matrix, extended W1E weights ----------------
// W1E[o][u] (K=288): u<64: f_rep W1 cols; 64..127: f_diff; 128..191: E_d=Wxd@Wm;
// 192..255: E_r=Wxr@Wm; 256: w1b=Wxr@bmlp; 257..287: 0.   cp(c)=(c%48)*4+c/48.
__global__ __launch_bounds__(256) void k_prep(const float* __restrict__ A,
                                              const float* __restrict__ kern,
                                              const float* __restrict__ W1,
                                              const float* __restrict__ Wmlp,
                                              const float* __restrict__ bmlp,
                                              const float* __restrict__ mmPart,
                                              float* __restrict__ scal,
                                              unsigned short* __restrict__ W1E) {
  __shared__ float smn[256], smx[256];
  const int t = threadIdx.x;
  float mn = 1e30f, mx = -1e30f;
  for (int i = t; i < 4096; i += 256) {
    mn = fminf(mn, mmPart[i * 2]);
    mx = fmaxf(mx, mmPart[i * 2 + 1]);
  }
  smn[t] = mn; smx[t] = mx;
  __syncthreads();
  for (int s = 128; s > 0; s >>= 1) {
    if (t < s) { smn[t] = fminf(smn[t], smn[t + s]); smx[t] = fmaxf(smx[t], smx[t + s]); }
    __syncthreads();
  }
  if (t == 0) scal[0] = smn[0] / (smx[0] - smn[0]);   // c  (ref precedence: x - mn/(mx-mn))
  if (t < 24) {
    int d = t >> 3, e = t & 7;
    float s = 0.f;
    for (int d2 = 0; d2 < 3; ++d2)
      s += 0.5f * (A[d * 3 + d2] + A[d2 * 3 + d]) * kern[d2 * 8 + e];
    scal[1 + t] = s;
  }
  for (int i = t; i < 18432; i += 256) {
    int o = i / 288, u = i % 288;
    float v;
    if (u < 64) {
      int c = u;
      v = W1[o * 192 + (c % 48) * 4 + c / 48];
    } else if (u < 128) {
      int c = 96 + (u - 64);
      v = W1[o * 192 + (c % 48) * 4 + c / 48];
    } else if (u < 192) {
      int m = u - 128; float s = 0.f;
      for (int j = 0; j < 32; ++j) {
        int c = 160 + j;
        s += W1[o * 192 + (c % 48) * 4 + c / 48] * Wmlp[j * 64 + m];
      }
      v = s;
    } else if (u < 256) {
      int m = u - 192; float s = 0.f;
      for (int j = 0; j < 32; ++j) {
        int c = 64 + j;
        s += W1[o * 192 + (c % 48) * 4 + c / 48] * Wmlp[j * 64 + m];
      }
      v = s;
    } else if (u == 256) {
      float s = 0.f;
      for (int j = 0; j < 32; ++j) {
        int c = 64 + j;
        s += W1[o * 192 + (c % 48) * 4 + c / 48] * bmlp[j];
      }
      v = s;
    } else {
      v = 0.f;
    }
    W1E[o * 288 + u] = f2bf(v);
  }
}

// ---------------- K2: transpose feature (B,64,N) -> featN (B,N,64) ----------------
__global__ __launch_bounds__(256) void k_transpose(const float* __restrict__ f,
                                                   float* __restrict__ fN) {
  __shared__ float tile[64][65];
  const int b = blockIdx.y, n0 = blockIdx.x * 64, t = threadIdx.x;
  const float* fb = f + (size_t)b * 64 * 2048;
  for (int i = t; i < 4096; i += 256) {
    int c = i >> 6, nl = i & 63;
    tile[c][nl] = fb[c * 2048 + n0 + nl];
  }
  __syncthreads();
  float* out = fN + ((size_t)b * 2048 + n0) * 64;
  for (int i = t; i < 4096; i += 256) {
    int nl = i >> 6, c = i & 63;
    out[nl * 64 + c] = tile[c][nl];
  }
}

// ---------------- K3: main — ff in regs, 64-lane softmax, x-path folded into h-GEMM ----------------
// LDS: aggB 32*296*2=18944 + recL 1408 + permL 2560 + selfFL 1024 + colsumL 128 = 24064 B
// __launch_bounds__(256, 4): min 4 waves/EU -> 128-VGPR budget. R8's (256,6)
// capped VGPRs at ~84 and SPILLED gv[20]+ffk[20] to scratch (4.5 GB traffic,
// 7x regression). Occupancy is register-limited ~5 blocks/CU, LDS allows 6.
__global__ __launch_bounds__(256, 4) void k_main(const float* __restrict__ rec,
    const int* __restrict__ idxArr, const float* __restrict__ featN,
    const float* __restrict__ scal, const unsigned short* __restrict__ W1E,
    const float* __restrict__ Bf, const float* __restrict__ onePad,
    const float* __restrict__ b1, const float* __restrict__ Wout,
    float* __restrict__ hT) {
  __shared__ __align__(16) unsigned short aggB[32 * 296];
  __shared__ __align__(16) float recL[4][88];
  __shared__ float permL[4][160];
  __shared__ float selfFL[4][64];
  __shared__ float colsumL[4][8];

  const int t = threadIdx.x;
  const int pt = t >> 6, lane = t & 63;
  const int row = blockIdx.x * 4 + pt;
  const int b = row >> 11;
  const int fr = lane & 15, fg = lane >> 4;
  const int m31 = lane & 31, e7 = lane & 7, k4 = lane >> 3;

  // ---- phase A: all global constants -> regs ----
  float bf_[7];
  #pragma unroll
  for (int d = 0; d < 7; ++d) bf_[d] = Bf[d * 32 + m31];
  const float c0 = scal[0];
  const float M0 = scal[1 + e7], M1 = scal[9 + e7], M2 = scal[17 + e7];
  const float op0v = onePad[lane];
  const float op1v = onePad[64 + lane];
  const float op2v = (lane < 32) ? onePad[128 + lane] : 0.f;
  const int ntb = (pt >> 1) * 2;
  const int col = (ntb + (fg & 1)) * 16 + fr;
  const float b1v = b1[col];

  // ---- phase B: per-row loads ----
  if (lane < 22)
    *(float4v*)&recL[pt][4 * lane] = *(const float4v*)(rec + (size_t)row * 88 + 4 * lane);
  selfFL[pt][lane] = featN[(size_t)row * 64 + lane];
  int myidx = (lane < 20) ? idxArr[(size_t)row * 20 + lane] : 0;

  // ---- phase C: issue all 20 gathers (consumed in agg, much later) ----
  float gv[20];
  {
    const float* fNb = featN + (((size_t)b << 11) * 64);
    #pragma unroll
    for (int k = 0; k < 20; ++k) {
      int j = __shfl(myidx, k);
      gv[k] = fNb[(size_t)j * 64 + lane];
    }
  }

  // zero aggB pad cols 257..287 of this wave's 8 rows (weights there are 0, but
  // keep A finite: uninitialized LDS could hold NaN; NaN*0 = NaN)
  if (lane >= 32 && lane < 63) {
    #pragma unroll
    for (int e = 0; e < 8; ++e)
      aggB[(pt * 8 + e) * 296 + 225 + lane] = 0;
  }
  wave_fence();   // recL visible (same wave)

  // ---- perm + topkmax softmax, 64-lane: lane = (k4 = lane>>3, e = lane&7) ----
  {
    float4v r0 = *(const float4v*)&recL[pt][4 + 4 * k4];
    float4v r1 = *(const float4v*)&recL[pt][4 + 4 * (k4 + 8)];
    float lg0 = fmaf(r0[1], M0, fmaf(r0[2], M1, fmaf(r0[3], M2, op0v)));
    float lg1 = fmaf(r1[1], M0, fmaf(r1[2], M1, fmaf(r1[3], M2, op1v)));
    float lg2 = -1e30f;
    if (lane < 32) {
      float4v r2 = *(const float4v*)&recL[pt][4 + 4 * (k4 + 16)];
      lg2 = fmaf(r2[1], M0, fmaf(r2[2], M1, fmaf(r2[3], M2, op2v)));
    }
    float mx = fmaxf(fmaxf(lg0, lg1), lg2);
    mx = fmaxf(mx, __shfl_xor(mx, 8));
    mx = fmaxf(mx, __shfl_xor(mx, 16));
    mx = fmaxf(mx, __shfl_xor(mx, 32));
    float e0 = __expf(lg0 - mx), e1 = __expf(lg1 - mx);
    float e2 = (lane < 32) ? __expf(lg2 - mx) : 0.f;
    float s1 = e0 + e1 + e2;
    s1 += __shfl_xor(s1, 8); s1 += __shfl_xor(s1, 16); s1 += __shfl_xor(s1, 32);
    float inv = 1.f / s1;
    float q0 = e0 * inv, q1 = e1 * inv, q2 = e2 * inv;
    q0 = (q0 > 0.05f) ? q0 : 0.f;
    q1 = (q1 > 0.05f) ? q1 : 0.f;
    q2 = (q2 > 0.05f) ? q2 : 0.f;
    float s2 = q0 + q1 + q2;
    s2 += __shfl_xor(s2, 8); s2 += __shfl_xor(s2, 16); s2 += __shfl_xor(s2, 32);
    float inv2 = 1.f / (s2 + 1e-6f);
    permL[pt][lane]      = q0 * inv2;
    permL[pt][64 + lane] = q1 * inv2;
    if (lane < 32) permL[pt][128 + lane] = q2 * inv2;
    if (k4 == 0) colsumL[pt][e7] = s2 * inv2;
  }

  // ---- Fourier features, fully in registers: lane = m (0..31 sin, 32..63 cos) ----
  float ffk[20];
  {
    const float sumB = ((bf_[0] + bf_[1]) + (bf_[2] + bf_[3]))
                     + ((bf_[4] + bf_[5]) + bf_[6]);
    float basev = recL[pt][0] * bf_[0];
    basev = fmaf(recL[pt][1], bf_[1], basev);
    basev = fmaf(recL[pt][2], bf_[2], basev);
    basev = fmaf(-c0, sumB, basev);
    const bool iscos = (lane >= 32);
    #pragma unroll
    for (int k = 0; k < 20; ++k) {
      float4v r4 = *(const float4v*)&recL[pt][4 + 4 * k];
      float s = basev;
      s = fmaf(r4[1], bf_[3], s);
      s = fmaf(r4[2], bf_[4], s);
      s = fmaf(r4[3], bf_[5], s);
      s = fmaf(r4[0], bf_[6], s);
      float fs, sv, cv;
      asm("v_fract_f32 %0, %1" : "=v"(fs) : "v"(s));
      asm("v_sin_f32 %0, %1"   : "=v"(sv) : "v"(fs));
      asm("v_cos_f32 %0, %1"   : "=v"(cv) : "v"(fs));
      ffk[k] = iscos ? cv : sv;
    }
  }
  wave_fence();   // permL / colsumL visible (same wave)

  // ---- agg: accQ (x-path) and accF (f_neigh) in one pass over perm ----
  float cs[8];
  {
    float4v c01 = *(const float4v*)&colsumL[pt][0];
    float4v c23 = *(const float4v*)&colsumL[pt][4];
    cs[0] = c01[0]; cs[1] = c01[1]; cs[2] = c01[2]; cs[3] = c01[3];
    cs[4] = c23[0]; cs[5] = c23[1]; cs[6] = c23[2]; cs[7] = c23[3];
  }
  float accQ[8], accF[8];
  #pragma unroll
  for (int e = 0; e < 8; ++e) { accQ[e] = 0.f; accF[e] = 0.f; }
  #pragma unroll
  for (int k = 0; k < 20; ++k) {
    float4v p0 = *(const float4v*)&permL[pt][k * 8];
    float4v p1 = *(const float4v*)&permL[pt][k * 8 + 4];
    const float fv = ffk[k], gvv = gv[k];
    accQ[0] = fmaf(fv, p0[0], accQ[0]); accQ[1] = fmaf(fv, p0[1], accQ[1]);
    accQ[2] = fmaf(fv, p0[2], accQ[2]); accQ[3] = fmaf(fv, p0[3], accQ[3]);
    accQ[4] = fmaf(fv, p1[0], accQ[4]); accQ[5] = fmaf(fv, p1[1], accQ[5]);
    accQ[6] = fmaf(fv, p1[2], accQ[6]); accQ[7] = fmaf(fv, p1[3], accQ[7]);
    accF[0] = fmaf(gvv, p0[0], accF[0]); accF[1] = fmaf(gvv, p0[1], accF[1]);
    accF[2] = fmaf(gvv, p0[2], accF[2]); accF[3] = fmaf(gvv, p0[3], accF[3]);
    accF[4] = fmaf(gvv, p1[0], accF[4]); accF[5] = fmaf(gvv, p1[1], accF[5]);
    accF[6] = fmaf(gvv, p1[2], accF[6]); accF[7] = fmaf(gvv, p1[3], accF[7]);
  }

  // ---- aggB writes: [f_rep | f_diff | Q-ff0cs | ff0cs | cs | 0pad] ----
  {
    const float f0 = gv[0], x0 = ffk[0];
    #pragma unroll
    for (int e = 0; e < 8; ++e) {
      unsigned short* rb = aggB + (size_t)(pt * 8 + e) * 296;
      const float cse = cs[e];
      const float frep = f0 * cse;
      const float xrep = x0 * cse;
      rb[lane]       = f2bf(frep);
      rb[64 + lane]  = f2bf(accF[e] - frep);
      rb[128 + lane] = f2bf(accQ[e] - xrep);
      rb[192 + lane] = f2bf(xrep);
      if (lane == 0) rb[256] = f2bf(cse);
    }
  }
  __syncthreads();

  // ---- h-stage MFMA: (32 rows x 288) @ W1E^T(288 x 64) ----
  const int mt = pt & 1;
  float4v h0 = float4v{0.f, 0.f, 0.f, 0.f};
  float4v h1 = float4v{0.f, 0.f, 0.f, 0.f};
  {
    const unsigned short* aRow = aggB + (mt * 16 + fr) * 296;
    const unsigned short* w1p0 = W1E + ((ntb * 16 + fr) * 288);
    const unsigned short* w1p1 = W1E + (((ntb + 1) * 16 + fr) * 288);
    #pragma unroll
    for (int ks = 0; ks < 9; ++ks) {
      short8v a   = *(const short8v*)(aRow + ks * 32 + fg * 8);
      short8v b0  = *(const short8v*)(w1p0 + ks * 32 + fg * 8);
      short8v b1f = *(const short8v*)(w1p1 + ks * 32 + fg * 8);
      h0 = __builtin_amdgcn_mfma_f32_16x16x32_bf16(a, b0,  h0, 0, 0, 0);
      h1 = __builtin_amdgcn_mfma_f32_16x16x32_bf16(a, b1f, h1, 0, 0, 0);
    }
  }

  // ---- post: max over e (4 local + shfl16), +b1, gelu, residual, store ----
  {
    float m0 = fmaxf(fmaxf(h0[0], h0[1]), fmaxf(h0[2], h0[3]));
    float m1 = fmaxf(fmaxf(h1[0], h1[1]), fmaxf(h1[2], h1[3]));
    m0 = fmaxf(m0, __shfl_xor(m0, 16));
    m1 = fmaxf(m1, __shfl_xor(m1, 16));
    const int p_loc = 2 * mt + (fg >> 1);
    float hm = ((fg & 1) ? m1 : m0) + b1v;
    float g = 0.5f * hm * (1.f + erff(hm * 0.7071067811865476f));
    float res = 0.f;
    const float* wr = Wout + col * 64;
    #pragma unroll
    for (int c = 0; c < 64; c += 4) {
      float4 wv = *(const float4*)(wr + c);
      res = fmaf(wv.x, selfFL[p_loc][c],     res);
      res = fmaf(wv.y, selfFL[p_loc][c + 1], res);
      res = fmaf(wv.z, selfFL[p_loc][c + 2], res);
      res = fmaf(wv.w, selfFL[p_loc][c + 3], res);
    }
    hT[(size_t)(blockIdx.x * 4 + p_loc) * 64 + col] = g + res;
  }
}

// ---------------- K4: BN statistics (deterministic two-stage) ----------------
__global__ __launch_bounds__(256) void k_bnstat(const float* __restrict__ hT,
                                                float* __restrict__ part) {
  const int bk = blockIdx.x;
  const int t = threadIdx.x;
  const int o = t & 63, rg = t >> 6;
  float s = 0.f, s2 = 0.f;
  for (int r = bk * 512 + rg; r < (bk + 1) * 512; r += 4) {
    float v = hT[(size_t)r * 64 + o];
    s += v;
    s2 = fmaf(v, v, s2);
  }
  __shared__ float ls[256], ls2[256];
  ls[t] = s; ls2[t] = s2;
  __syncthreads();
  if (t < 64) {
    float a  = ls[t] + ls[t + 64] + ls[t + 128] + ls[t + 192];
    float a2 = ls2[t] + ls2[t + 64] + ls2[t + 128] + ls2[t + 192];
    part[(bk * 64 + t) * 2]     = a;
    part[(bk * 64 + t) * 2 + 1] = a2;
  }
}

__global__ void k_bnfinal(const float* __restrict__ part, float* __restrict__ stats) {
  const int t = threadIdx.x;
  if (t < 64) {
    float s = 0.f, s2 = 0.f;
    for (int bk = 0; bk < 64; ++bk) {
      s  += part[(bk * 64 + t) * 2];
      s2 += part[(bk * 64 + t) * 2 + 1];
    }
    float mu  = s * (1.f / 32768.f);
    float var = s2 * (1.f / 32768.f) - mu * mu;
    stats[t * 2]     = mu;
    stats[t * 2 + 1] = 1.f / sqrtf(var + 1e-5f);
  }
}

// ---------------- K5: BN apply + transpose to (B,64,N) ----------------
__global__ __launch_bounds__(256) void k_bnapply(const float* __restrict__ hT,
                                                 const float* __restrict__ stats,
                                                 const float* __restrict__ gamma,
                                                 const float* __restrict__ beta,
                                                 float* __restrict__ out) {
  __shared__ float tile[64][65];
  __shared__ float sMu[64], sRs[64], sGa[64], sBe[64];
  const int t = threadIdx.x;
  const int r0 = blockIdx.x * 64;
  if (t < 64) {
    sMu[t] = stats[t * 2];
    sRs[t] = stats[t * 2 + 1];
    sGa[t] = gamma[t];
    sBe[t] = beta[t];
  }
  __syncthreads();
  for (int i = t; i < 4096; i += 256) {
    int rl = i >> 6, o = i & 63;
    float v = hT[(size_t)(r0 + rl) * 64 + o];
    tile[rl][o] = fmaf((v - sMu[o]) * sRs[o], sGa[o], sBe[o]);
  }
  __syncthreads();
  const int b = r0 >> 11, n0 = r0 & 2047;
  for (int i = t; i < 4096; i += 256) {
    int o = i >> 6, nl = i & 63;
    out[((size_t)b * 64 + o) * 2048 + n0 + nl] = tile[nl][o];
  }
}

// ---------------- launch ----------------
extern "C" void kernel_launch(void* const* d_in, const int* in_sizes, int n_in,
                              void* d_out, int out_size, void* d_ws, size_t ws_size,
                              hipStream_t stream) {
  const float* x       = (const float*)d_in[0];
  const float* feature = (const float*)d_in[1];
  const float* A       = (const float*)d_in[2];
  const float* Bf      = (const float*)d_in[3];
  const float* kern    = (const float*)d_in[4];
  const float* onePad  = (const float*)d_in[5];
  const float* Wmlp    = (const float*)d_in[6];
  const float* bmlp    = (const float*)d_in[7];
  const float* W1      = (const float*)d_in[8];
  const float* b1      = (const float*)d_in[9];
  const float* gamma   = (const float*)d_in[10];
  const float* beta    = (const float*)d_in[11];
  const float* Wout    = (const float*)d_in[12];

  char* ws = (char*)d_ws;
  float* rec           = (float*)(ws);                       // 11,534,336
  int*   idxA          = (int*)  (ws + 11534336);            // -> 14,155,776
  float* featN         = (float*)(ws + 14155776);            // -> 22,544,384
  float* hT            = (float*)(ws + 22544384);            // -> 30,932,992
  unsigned short* W1E  = (unsigned short*)(ws + 30932992);   // 36,864 -> 30,969,856
  float* mmPart        = (float*)(ws + 30969856);            // 32,768 -> 31,002,624
  float* scal          = (float*)(ws + 31002624);            // 256    -> 31,002,880
  float* bnPart        = (float*)(ws + 31002880);            // 32,768 -> 31,035,648
  float* bnStats       = (float*)(ws + 31035648);            // 512    -> 31,036,160

  k_knn<<<dim3(256, 16), 512, 0, stream>>>(x, rec, idxA, mmPart);
  k_prep<<<1, 256, 0, stream>>>(A, kern, W1, Wmlp, bmlp, mmPart, scal, W1E);
  k_transpose<<<dim3(32, 16), 256, 0, stream>>>(feature, featN);
  k_main<<<8192, 256, 0, stream>>>(rec, idxA, featN, scal, W1E,
                                   Bf, onePad, b1, Wout, hT);
  k_bnstat<<<64, 256, 0, stream>>>(hT, bnPart);
  k_bnfinal<<<1, 64, 0, stream>>>(bnPart, bnStats);
  k_bnapply<<<512, 256, 0, stream>>>(hT, bnStats, gamma, beta, (float*)d_out);
}